// Round 5
// baseline (431.810 us; speedup 1.0000x reference)
//
#include <hip/hip_runtime.h>

// DEQ fully register-resident, zero-LDS-storage, zero-barrier:
//   out = relu^{(30)}(z Wz^T + inj) @ Wd^T + bd,  inj = x Ux^T + b
//
// Each WAVE owns 16 batch rows and the FULL 128-wide hidden state:
//   D[n][m] = sum_k Wz[n][k] * z^T[k][m], n = 0..127 (8 MFMA tiles), m = l15.
// Wz lives in 128 regs/lane (unified VGPR+AGPR file). z is re-fed to the next
// iteration's B-operand entirely in-register:
//   D layout: lane(q,l) holds n = 16t + 4q + i  (i = reg 0..3)
//   B layout: lane(q,l) needs k = 32ks + 8q + j (j = 0..7)
//   => element j of frag[ks] comes from lane q_src=(2q+(j>>2))&3, tile
//      t = 2ks+(q>>1), reg i = j&3.  The t-parity split is v_permlane32_swap
//      (HW-verified round 1); the lane^16 exchange is ds_swizzle xor-16
//      (HW-verified round 1; the permlane16_swap variant FAILED numerically
//      in round 4 — do not reintroduce without a disasm session).
// ds_swizzle uses the LDS pipe but no LDS storage: LDS_Block_Size = 0.
//
// THE one change vs the verified round-1 kernel: __launch_bounds__(256, 2).
// Round 1 allocated 136 VGPR + 128 AGPR = 264 unified regs -> 1 wave/SIMD,
// fully exposed swizzle+MFMA latency (19.6% MfmaUtil). Capping at 256 gives
// 2 waves/SIMD; live set ~248 regs fits without loop spills.

typedef __attribute__((ext_vector_type(8))) __bf16 bf16x8;
typedef __attribute__((ext_vector_type(2))) __bf16 bf16x2;
typedef __attribute__((ext_vector_type(4))) float  floatx4;

#define MFMA16(a, b, c) __builtin_amdgcn_mfma_f32_16x16x32_bf16((a), (b), (c), 0, 0, 0)

static constexpr int kBsz = 262144;

__device__ __forceinline__ bf16x8 cvt_bf16x8(float4 a, float4 b) {
  bf16x8 r;
  r[0] = (__bf16)a.x; r[1] = (__bf16)a.y; r[2] = (__bf16)a.z; r[3] = (__bf16)a.w;
  r[4] = (__bf16)b.x; r[5] = (__bf16)b.y; r[6] = (__bf16)b.z; r[7] = (__bf16)b.w;
  return r;
}

__device__ __forceinline__ unsigned pk_relu2(float a, float b) {
  union { bf16x2 h; unsigned u; } x;
  x.h[0] = (__bf16)fmaxf(a, 0.0f);
  x.h[1] = (__bf16)fmaxf(b, 0.0f);
  return x.u;
}

union Frag { bf16x8 v; unsigned w[4]; };

// Build B-frag for k-chunk ks from packed z of tiles (2ks, 2ks+1).
// ulo/vlo = lo-words (regs i0,i1) of tiles 2ks / 2ks+1; uhi/vhi = hi-words.
__device__ __forceinline__ bf16x8 build_frag(unsigned ulo, unsigned vlo,
                                             unsigned uhi, unsigned vhi,
                                             bool qodd) {
  // after swap: u = {u.lo32, v.lo32}, v = {u.hi32, v.hi32}
  asm("v_permlane32_swap_b32 %0, %1" : "+v"(ulo), "+v"(vlo));
  asm("v_permlane32_swap_b32 %0, %1" : "+v"(uhi), "+v"(vhi));
  const unsigned c0 = qodd ? vlo : ulo;   // self-source word
  const unsigned d0 = qodd ? ulo : vlo;   // word the lane^16 partner needs
  const unsigned c1 = qodd ? vhi : uhi;
  const unsigned d1 = qodd ? uhi : vhi;
  const unsigned dx0 = __builtin_amdgcn_ds_swizzle((int)d0, 0x401F); // lane ^= 16
  const unsigned dx1 = __builtin_amdgcn_ds_swizzle((int)d1, 0x401F);
  Frag f;
  f.w[0] = qodd ? dx0 : c0;  // j=0,1 (A-source, regs i0,i1)
  f.w[1] = qodd ? dx1 : c1;  // j=2,3 (A-source, regs i2,i3)
  f.w[2] = qodd ? c0 : dx0;  // j=4,5 (B-source, regs i0,i1)
  f.w[3] = qodd ? c1 : dx1;  // j=6,7 (B-source, regs i2,i3)
  return f.v;
}

__global__ void __launch_bounds__(256, 2) deq_fused(
    const float* __restrict__ x,    // [B,64]
    const float* __restrict__ Wz,   // [128,128]
    const float* __restrict__ Ux,   // [128,64]
    const float* __restrict__ bvec, // [128]
    const float* __restrict__ Wd,   // [64,128]
    const float* __restrict__ bd,   // [64]
    const int*  __restrict__ n_iters_p,
    float* __restrict__ out)        // [B,64]
{
  const int tid  = threadIdx.x;
  const int lane = tid & 63;
  const int wv   = tid >> 6;          // 0..3, independent waves
  const int l15  = lane & 15;
  const int quad = lane >> 4;         // 0..3
  const bool qodd = (quad & 1) != 0;
  const int  mrow = blockIdx.x * 64 + wv * 16 + l15;  // this lane's batch row
  const int  iters = *n_iters_p;

  // ---- inj[t] in C/D layout: reg i -> n = 16t + 4q + i, col m = l15 ----
  floatx4 inj[8];
#pragma unroll
  for (int t = 0; t < 8; ++t) {
    const float4 bv = *(const float4*)(bvec + 16 * t + 4 * quad);
    floatx4 v = {bv.x, bv.y, bv.z, bv.w};
    inj[t] = v;
  }
  {
    // x^T as B-frags (K=64 -> 2 k-chunks)
    bf16x8 bx[2];
#pragma unroll
    for (int ks = 0; ks < 2; ++ks) {
      const float4* p = (const float4*)(x + (size_t)mrow * 64 + 32 * ks + 8 * quad);
      bx[ks] = cvt_bf16x8(p[0], p[1]);
    }
#pragma unroll
    for (int t = 0; t < 8; ++t) {
#pragma unroll
      for (int ks = 0; ks < 2; ++ks) {
        const float4* p = (const float4*)(Ux + (16 * t + l15) * 64 + 32 * ks + 8 * quad);
        const bf16x8 a = cvt_bf16x8(p[0], p[1]);
        inj[t] = MFMA16(a, bx[ks], inj[t]);
      }
    }
  }

  // ---- Wz as A-frags, full 128x128, register/AGPR-resident (128 regs) ----
  bf16x8 awz[8][4];
#pragma unroll
  for (int t = 0; t < 8; ++t)
#pragma unroll
    for (int ks = 0; ks < 4; ++ks) {
      const float4* p = (const float4*)(Wz + (16 * t + l15) * 128 + 32 * ks + 8 * quad);
      awz[t][ks] = cvt_bf16x8(p[0], p[1]);
    }

  // ---- z1 = relu(inj) packed: lo = (i0,i1), hi = (i2,i3) per tile ----
  unsigned lo[8], hi[8];
#pragma unroll
  for (int t = 0; t < 8; ++t) {
    lo[t] = pk_relu2(inj[t][0], inj[t][1]);
    hi[t] = pk_relu2(inj[t][2], inj[t][3]);
  }

  // ---- fixed-point loop: zero LDS storage, zero barriers ----
  for (int it = 0; it < iters - 1; ++it) {
    floatx4 acc[8];
    {
      const bf16x8 f0 = build_frag(lo[0], lo[1], hi[0], hi[1], qodd);
#pragma unroll
      for (int t = 0; t < 8; ++t)
        acc[t] = MFMA16(awz[t][0], f0, inj[t]);   // C-in = inj, no copies
    }
#pragma unroll
    for (int ks = 1; ks < 4; ++ks) {
      const bf16x8 f = build_frag(lo[2 * ks], lo[2 * ks + 1],
                                  hi[2 * ks], hi[2 * ks + 1], qodd);
#pragma unroll
      for (int t = 0; t < 8; ++t)
        acc[t] = MFMA16(awz[t][ks], f, acc[t]);
    }
#pragma unroll
    for (int t = 0; t < 8; ++t) {
      lo[t] = pk_relu2(acc[t][0], acc[t][1]);
      hi[t] = pk_relu2(acc[t][2], acc[t][3]);
    }
  }

  // ---- decoder: D[o][m] = sum_k Wd[o][k] z^T[k][m] + bd ----
  bf16x8 bz[4];
#pragma unroll
  for (int ks = 0; ks < 4; ++ks)
    bz[ks] = build_frag(lo[2 * ks], lo[2 * ks + 1],
                        hi[2 * ks], hi[2 * ks + 1], qodd);
#pragma unroll
  for (int ot = 0; ot < 4; ++ot) {
    const float4 bv = *(const float4*)(bd + 16 * ot + 4 * quad);
    floatx4 acc = {bv.x, bv.y, bv.z, bv.w};
#pragma unroll
    for (int ks = 0; ks < 4; ++ks) {
      const float4* p = (const float4*)(Wd + (16 * ot + l15) * 128 + 32 * ks + 8 * quad);
      const bf16x8 a = cvt_bf16x8(p[0], p[1]);
      acc = MFMA16(a, bz[ks], acc);
    }
    float4 ov;
    ov.x = acc[0]; ov.y = acc[1]; ov.z = acc[2]; ov.w = acc[3];
    *(float4*)(out + (size_t)mrow * 64 + 16 * ot + 4 * quad) = ov;
  }
}

extern "C" void kernel_launch(void* const* d_in, const int* in_sizes, int n_in,
                              void* d_out, int out_size, void* d_ws, size_t ws_size,
                              hipStream_t stream) {
  const float* x  = (const float*)d_in[0];
  const float* Wz = (const float*)d_in[1];
  const float* Ux = (const float*)d_in[2];
  const float* b  = (const float*)d_in[3];
  const float* Wd = (const float*)d_in[4];
  const float* bd = (const float*)d_in[5];
  const int* n_it = (const int*)d_in[6];
  float* outp = (float*)d_out;
  (void)in_sizes; (void)n_in; (void)d_ws; (void)ws_size; (void)out_size;

  dim3 grid(kBsz / 64);  // 4096 blocks x 4 independent waves, 16 rows/wave
  deq_fused<<<grid, 256, 0, stream>>>(x, Wz, Ux, b, Wd, bd, n_it, outp);
}